// Round 8
// baseline (95.917 us; speedup 1.0000x reference)
//
#include <hip/hip_runtime.h>
#include <stdint.h>

typedef unsigned short u16;
typedef unsigned int u32;
typedef unsigned long long u64;

typedef __bf16 bf16x8 __attribute__((ext_vector_type(8)));
typedef float f32x4 __attribute__((ext_vector_type(4)));
typedef u16 u16x8 __attribute__((ext_vector_type(8)));

#define NQ 512
#define NC 16
#define NH 128
#define NB 2048
#define IPB 8               // items per block
#define NBLK (NB/IPB)       // 256 blocks = 1/CU
#define TSTRIDE 136         // sTab row stride in u16 (272 B, 16B-aligned rows, de-phased banks)
#define ESTRIDE 136         // sE row stride
#define HSTRIDE 16          // sHB row stride (32 B)
#define QE_KEYS (513*128)   // 65664 u16 keys
#define WT_OFF  QE_KEYS     // u16 offset of bf16 W copy in d_ws
#define GW_ELEMS (128*128)

static __device__ __forceinline__ u16 f2bf_rne(float f){
  u32 u = __float_as_uint(f);
  u += 0x7fffu + ((u>>16)&1u);
  return (u16)(u>>16);
}
static __device__ __forceinline__ u32 pack_rne(float lo, float hi){
  return (u32)f2bf_rne(lo) | ((u32)f2bf_rne(hi)<<16);
}
// monotone key: unsigned compare on keys == float compare on bf16 values
static __device__ __forceinline__ u16 key_of(float f){
  u16 b = f2bf_rne(f);
  return (b & 0x8000u) ? (u16)~b : (u16)(b | 0x8000u);
}
static __device__ __forceinline__ u16 unkey(u16 k){
  return (k & 0x8000u) ? (u16)(k ^ 0x8000u) : (u16)~k;
}

union Frag { u32 u[4]; uint4 u4; bf16x8 f; };
union U8   { u16x8 v; int w[4]; uint4 u4; u16 h[8]; };

// ---- prepass: qe fp32 -> u16 keys (row 512 forced to key(0)=0x8000); gw fp32 -> bf16 ----
__global__ void prepass_kernel(const float* __restrict__ qe,
                               const float* __restrict__ gw,
                               u16* __restrict__ ws)
{
  int idx = blockIdx.x * 256 + threadIdx.x;
  if (idx < QE_KEYS/8) {                       // key table
    int i8 = idx * 8;
    uint4 o;
    if (i8 >= 512*NH) {                        // row 512: key of +0.0
      o.x = 0x80008000u; o.y = 0x80008000u; o.z = 0x80008000u; o.w = 0x80008000u;
    } else {
      const float4* p = (const float4*)(qe + i8);
      float4 a = p[0], b = p[1];
      o.x = (u32)key_of(a.x) | ((u32)key_of(a.y)<<16);
      o.y = (u32)key_of(a.z) | ((u32)key_of(a.w)<<16);
      o.z = (u32)key_of(b.x) | ((u32)key_of(b.y)<<16);
      o.w = (u32)key_of(b.z) | ((u32)key_of(b.w)<<16);
    }
    *(uint4*)(ws + i8) = o;
  } else if (idx < QE_KEYS/8 + GW_ELEMS/8) {   // W -> bf16
    int j8 = (idx - QE_KEYS/8) * 8;
    const float4* p = (const float4*)(gw + j8);
    float4 a = p[0], b = p[1];
    uint4 o;
    o.x = pack_rne(a.x, a.y); o.y = pack_rne(a.z, a.w);
    o.z = pack_rne(b.x, b.y); o.w = pack_rne(b.z, b.w);
    *(uint4*)(ws + WT_OFF + j8) = o;
  }
}

static __device__ __forceinline__ void wave_reduce_max(U8& A){
  U8 B;
  #pragma unroll
  for (int j = 0; j < 4; ++j) B.w[j] = __shfl_xor(A.w[j], 16);
  A.v = __builtin_elementwise_max(A.v, B.v);
  #pragma unroll
  for (int j = 0; j < 4; ++j) B.w[j] = __shfl_xor(A.w[j], 32);
  A.v = __builtin_elementwise_max(A.v, B.v);
}

__global__ __launch_bounds__(1024, 4)
void core_snapshot_kernel(const int* __restrict__ la,
                          const float* __restrict__ adj,
                          const u16* __restrict__ ws,   // keys + bf16 W
                          const float* __restrict__ gb,
                          float* __restrict__ outp)
{
  // total static LDS: 139536+4096+8704+8192+1024+1024+128+64 = 162768 B (<=163840)
  __shared__ __align__(16) u16 sTab[513*TSTRIDE];    // full key table, padded rows
  __shared__ __align__(16) u16 sList[2][16*64];      // per-team transposed slot lists
  __shared__ __align__(16) u16 sE[2][16*ESTRIDE];    // core_embs (bf16)
  __shared__ __align__(16) u16 sHB[2][128*HSTRIDE];  // H transposed: [o][core]
  __shared__ u32 sHist[2][8*16];
  __shared__ u32 sBase[2][8*16];
  __shared__ u32 sCnt[2][16];
  __shared__ float sDinv[16];

  const int tid  = threadIdx.x;
  const int lane = tid & 63;
  const int wv   = tid >> 6;      // 0..15
  const int team = wv >> 3;       // 0/1: one item each per pair
  const int wt8  = wv & 7;        // wave-in-team
  const int m    = lane & 15;
  const int quad = lane >> 4;
  const u16* wt  = ws + WT_OFF;   // bf16 W, row-major [o][h]

  // ---- stage full key table into LDS (once per block; rows re-padded to TSTRIDE) ----
  {
    const uint4* src = (const uint4*)ws;        // 8208 uint4
    #pragma unroll
    for (int i = 0; i < 9; ++i) {
      int idx = tid + i*1024;
      if (idx < QE_KEYS/8) {
        uint4 v = src[idx];
        int row = idx >> 4, col8 = (idx & 15) << 3;
        *(uint4*)&sTab[row*TSTRIDE + col8] = v;
      }
    }
  }
  if (tid < 16) {   // dinv from adjacency column sums
    float s = 0.f;
    for (int i = 0; i < 16; ++i) s += adj[i*16 + tid];
    sDinv[tid] = (s > 0.f) ? (1.0f / sqrtf(s)) : 0.f;
  }
  __syncthreads();

  // ---- A_norm MFMA A-fragment (K padded 16->32) + bias, constant across pairs ----
  Frag afr2;
  #pragma unroll
  for (int jj = 0; jj < 4; ++jj) {
    float lo = 0.f, hi = 0.f;
    if (quad < 2) {
      int k0 = quad*8 + jj*2;
      lo = adj[m*16 + k0]     * sDinv[m] * sDinv[k0];
      hi = adj[m*16 + k0 + 1] * sDinv[m] * sDinv[k0 + 1];
    }
    afr2.u[jj] = pack_rne(lo, hi);
  }
  const int ocol = wt8*16 + m;          // this wave's o-tile column
  const float biasv = gb[ocol];
  const u64 lmask = (1ull << lane) - 1ull;

  for (int pair = 0; pair < IPB/2; ++pair) {
    const int item = blockIdx.x*IPB + pair*2 + team;

    // prefill sList with 512 (pads gather key-0 row) — safe: sList idle since last phase2
    if (tid < 256)
      ((uint4*)sList)[tid] = make_uint4(0x02000200u,0x02000200u,0x02000200u,0x02000200u);

    // ---- phase 1: this wave = chunk wt8 of its team's item ----
    const int avv = la[item*NQ + wt8*64 + lane];
    u32 intra = 0;
    #pragma unroll
    for (int c = 0; c < 16; ++c) {
      u64 mk = __ballot(avv == c);
      if (lane == c) sHist[team][wt8*16 + c] = (u32)__popcll(mk);
      if (avv == c)  intra = (u32)__popcll(mk & lmask);
    }
    __syncthreads();
    if (tid < 32) {   // exclusive prefix over chunks (16 lanes per team)
      int t = tid >> 4, c = tid & 15;
      u32 run = 0;
      #pragma unroll
      for (int ch = 0; ch < 8; ++ch) { sBase[t][ch*16 + c] = run; run += sHist[t][ch*16 + c]; }
      sCnt[t][c] = run;
    }
    __syncthreads();
    {
      u32 rank = sBase[team][wt8*16 + avv] + intra;
      // transposed: quad q's 16 entries [q*16+k] hold ranks q+4k (contiguous 32 B)
      if (rank < 64) sList[team][avv*64 + (rank&3)*16 + (rank>>2)] = (u16)(wt8*64 + lane);
    }
    __syncthreads();

    // ---- phase 2: LDS gather, 2 cores per wave, batched ds_read_b128 ----
    {
      const int ca = wt8*2, cb = ca + 1;
      U8 Sa0, Sa1, Sb0, Sb1;
      Sa0.u4 = *(const uint4*)&sList[team][ca*64 + quad*16];
      Sa1.u4 = *(const uint4*)&sList[team][ca*64 + quad*16 + 8];
      Sb0.u4 = *(const uint4*)&sList[team][cb*64 + quad*16];
      Sb1.u4 = *(const uint4*)&sList[team][cb*64 + quad*16 + 8];
      const int cna = (int)sCnt[team][ca], cnb = (int)sCnt[team][cb];
      U8 A, B; A.v = (u16x8)0; B.v = (u16x8)0;     // key 0 < all value keys
      const u16* tb = sTab + m*8;                  // this lane's 8-dim chunk
      {  // ranks < 32: unconditional, 8+8 reads batched
        U8 Ta[4], Tb[4];
        #pragma unroll
        for (int k = 0; k < 4; ++k) {
          Ta[k].u4 = *(const uint4*)(tb + (int)Sa0.h[k]*TSTRIDE);
          Tb[k].u4 = *(const uint4*)(tb + (int)Sb0.h[k]*TSTRIDE);
        }
        #pragma unroll
        for (int k = 0; k < 4; ++k) {
          A.v = __builtin_elementwise_max(A.v, Ta[k].v);
          B.v = __builtin_elementwise_max(B.v, Tb[k].v);
        }
        #pragma unroll
        for (int k = 0; k < 4; ++k) {
          Ta[k].u4 = *(const uint4*)(tb + (int)Sa0.h[k+4]*TSTRIDE);
          Tb[k].u4 = *(const uint4*)(tb + (int)Sb0.h[k+4]*TSTRIDE);
        }
        #pragma unroll
        for (int k = 0; k < 4; ++k) {
          A.v = __builtin_elementwise_max(A.v, Ta[k].v);
          B.v = __builtin_elementwise_max(B.v, Tb[k].v);
        }
      }
      if (cna > 32) {   // ranks 32..63, wave-uniform branch
        U8 Ta[8];
        #pragma unroll
        for (int k = 0; k < 8; ++k) Ta[k].u4 = *(const uint4*)(tb + (int)Sa1.h[k]*TSTRIDE);
        #pragma unroll
        for (int k = 0; k < 8; ++k) A.v = __builtin_elementwise_max(A.v, Ta[k].v);
      }
      if (cnb > 32) {
        U8 Tb[8];
        #pragma unroll
        for (int k = 0; k < 8; ++k) Tb[k].u4 = *(const uint4*)(tb + (int)Sb1.h[k]*TSTRIDE);
        #pragma unroll
        for (int k = 0; k < 8; ++k) B.v = __builtin_elementwise_max(B.v, Tb[k].v);
      }
      wave_reduce_max(A);
      wave_reduce_max(B);
      U8 Z; Z.v = (u16x8)(u16)0x8000u;             // key(+0): relu for under-full cores
      if (cna < 64) A.v = __builtin_elementwise_max(A.v, Z.v);
      if (cnb < 64) B.v = __builtin_elementwise_max(B.v, Z.v);
      if (quad == 0) {
        uint4 e;
        e.x = (u32)unkey(A.h[0]) | ((u32)unkey(A.h[1])<<16);
        e.y = (u32)unkey(A.h[2]) | ((u32)unkey(A.h[3])<<16);
        e.z = (u32)unkey(A.h[4]) | ((u32)unkey(A.h[5])<<16);
        e.w = (u32)unkey(A.h[6]) | ((u32)unkey(A.h[7])<<16);
        *(uint4*)&sE[team][ca*ESTRIDE + m*8] = e;
        e.x = (u32)unkey(B.h[0]) | ((u32)unkey(B.h[1])<<16);
        e.y = (u32)unkey(B.h[2]) | ((u32)unkey(B.h[3])<<16);
        e.z = (u32)unkey(B.h[4]) | ((u32)unkey(B.h[5])<<16);
        e.w = (u32)unkey(B.h[6]) | ((u32)unkey(B.h[7])<<16);
        *(uint4*)&sE[team][cb*ESTRIDE + m*8] = e;
      }
    }
    __syncthreads();

    // ---- phase 3: H = E @ W^T via MFMA -> sHB[o][core]; one 16-o tile per wave ----
    {
      bf16x8 af[4];
      #pragma unroll
      for (int ks = 0; ks < 4; ++ks)
        af[ks] = *(const bf16x8*)&sE[team][m*ESTRIDE + ks*32 + quad*8];
      f32x4 acc = {0.f, 0.f, 0.f, 0.f};
      #pragma unroll
      for (int ks = 0; ks < 4; ++ks) {
        bf16x8 bfr = *(const bf16x8*)(wt + ocol*NH + ks*32 + quad*8);
        acc = __builtin_amdgcn_mfma_f32_16x16x32_bf16(af[ks], bfr, acc, 0, 0, 0);
      }
      // C/D layout: col=lane&15 (o in tile), row=quad*4+reg (core)
      *(u32*)&sHB[team][ocol*HSTRIDE + quad*4]     = pack_rne(acc[0], acc[1]);
      *(u32*)&sHB[team][ocol*HSTRIDE + quad*4 + 2] = pack_rne(acc[2], acc[3]);
    }
    __syncthreads();

    // ---- phase 4: out = A_norm @ H + bias (K padded 16->32) ----
    {
      Frag bfr;
      if (quad < 2) bfr.u4 = *(const uint4*)&sHB[team][ocol*HSTRIDE + quad*8];
      else { bfr.u[0]=0; bfr.u[1]=0; bfr.u[2]=0; bfr.u[3]=0; }
      f32x4 acc = {biasv, biasv, biasv, biasv};
      acc = __builtin_amdgcn_mfma_f32_16x16x32_bf16(afr2.f, bfr.f, acc, 0, 0, 0);
      float* op = outp + item*(NC*NH) + ocol;
      #pragma unroll
      for (int r = 0; r < 4; ++r) op[(quad*4 + r)*NH] = acc[r];
    }
    __syncthreads();   // sHB/sList safe before next pair's writes
  }
}

extern "C" void kernel_launch(void* const* d_in, const int* in_sizes, int n_in,
                              void* d_out, int out_size, void* d_ws, size_t ws_size,
                              hipStream_t stream) {
  const int*   la  = (const int*)d_in[0];    // (2048, 512) int32
  const float* adj = (const float*)d_in[1];  // (16,16) fp32
  const float* qe  = (const float*)d_in[2];  // (513,128) fp32
  const float* gw  = (const float*)d_in[3];  // (128,128) fp32
  const float* gb  = (const float*)d_in[4];  // (128,) fp32
  float* outp = (float*)d_out;               // (2048,16,128) fp32
  u16* ws = (u16*)d_ws;                      // keys (131328 B) + bf16 W (32768 B)

  int pre_threads = QE_KEYS/8 + GW_ELEMS/8;  // 10256
  prepass_kernel<<<(pre_threads + 255)/256, 256, 0, stream>>>(qe, gw, ws);
  core_snapshot_kernel<<<NBLK, 1024, 0, stream>>>(la, adj, ws, gb, outp);
}

// Round 9
// 92.637 us; speedup vs baseline: 1.0354x; 1.0354x over previous
//
#include <hip/hip_runtime.h>
#include <stdint.h>

typedef unsigned short u16;
typedef unsigned int u32;
typedef unsigned long long u64;

typedef __bf16 bf16x8 __attribute__((ext_vector_type(8)));
typedef float f32x4 __attribute__((ext_vector_type(4)));
typedef u16 u16x8 __attribute__((ext_vector_type(8)));

#define NQ 512
#define NC 16
#define NH 128
#define NB 2048
#define QE_KEYS (513*128)          // 65664 u16 keys
#define WT_OFF  QE_KEYS            // bf16 W copy
#define GW_ELEMS (128*128)
#define A_OFF (WT_OFF + GW_ELEMS)  // a_norm bf16, padded 16x32 (K 16->32 zeros)
#define LSEG 1088                  // per-wave list segment (16*64=1024 + pad), u16
#define ESEG 2304                  // per-wave sE segment (16*136=2176 + pad), u16
#define ESTRIDE 136

static __device__ __forceinline__ u16 f2bf_rne(float f){
  u32 u = __float_as_uint(f);
  u += 0x7fffu + ((u>>16)&1u);
  return (u16)(u>>16);
}
static __device__ __forceinline__ u32 pack_rne(float lo, float hi){
  return (u32)f2bf_rne(lo) | ((u32)f2bf_rne(hi)<<16);
}
// monotone key: unsigned compare on keys == float compare on bf16 values
static __device__ __forceinline__ u16 key_of(float f){
  u16 b = f2bf_rne(f);
  return (b & 0x8000u) ? (u16)~b : (u16)(b | 0x8000u);
}
static __device__ __forceinline__ u16 unkey(u16 k){
  return (k & 0x8000u) ? (u16)(k ^ 0x8000u) : (u16)~k;
}

union Frag { u32 u[4]; uint4 u4; bf16x8 f; };
union U8   { u16x8 v; int w[4]; uint4 u4; u16 h[8]; };

// ---- prepass: keys, bf16 W, and precomputed a_norm A-fragment table ----
__global__ void prepass_kernel(const float* __restrict__ qe,
                               const float* __restrict__ gw,
                               const float* __restrict__ adj,
                               u16* __restrict__ ws)
{
  if (blockIdx.x == 0) {            // a_norm = adj * dinv_i * dinv_j, padded 16x32
    __shared__ float sD[16];
    int t = threadIdx.x;
    if (t < 16) {
      float s = 0.f;
      for (int i = 0; i < 16; ++i) s += adj[i*16 + t];
      sD[t] = (s > 0.f) ? (1.0f / sqrtf(s)) : 0.f;
    }
    __syncthreads();
    int i = t >> 4, jp = (t & 15) * 2;   // row i, cols jp, jp+1 of 32
    float lo = (jp   < 16) ? adj[i*16 + jp]   * sD[i] * sD[jp]   : 0.f;
    float hi = (jp+1 < 16) ? adj[i*16 + jp+1] * sD[i] * sD[jp+1] : 0.f;
    ((u32*)(ws + A_OFF))[t] = pack_rne(lo, hi);
    return;
  }
  int idx = (blockIdx.x - 1) * 256 + threadIdx.x;
  if (idx < QE_KEYS/8) {                       // key table
    int i8 = idx * 8;
    uint4 o;
    if (i8 >= 512*NH) {                        // row 512: key of +0.0
      o.x = 0x80008000u; o.y = 0x80008000u; o.z = 0x80008000u; o.w = 0x80008000u;
    } else {
      const float4* p = (const float4*)(qe + i8);
      float4 a = p[0], b = p[1];
      o.x = (u32)key_of(a.x) | ((u32)key_of(a.y)<<16);
      o.y = (u32)key_of(a.z) | ((u32)key_of(a.w)<<16);
      o.z = (u32)key_of(b.x) | ((u32)key_of(b.y)<<16);
      o.w = (u32)key_of(b.z) | ((u32)key_of(b.w)<<16);
    }
    *(uint4*)(ws + i8) = o;
  } else if (idx < QE_KEYS/8 + GW_ELEMS/8) {   // W -> bf16
    int j8 = (idx - QE_KEYS/8) * 8;
    const float4* p = (const float4*)(gw + j8);
    float4 a = p[0], b = p[1];
    uint4 o;
    o.x = pack_rne(a.x, a.y); o.y = pack_rne(a.z, a.w);
    o.z = pack_rne(b.x, b.y); o.w = pack_rne(b.z, b.w);
    *(uint4*)(ws + WT_OFF + j8) = o;
  }
}

static __device__ __forceinline__ void wave_reduce_max(U8& A){
  U8 B;
  #pragma unroll
  for (int j = 0; j < 4; ++j) B.w[j] = __shfl_xor(A.w[j], 16);
  A.v = __builtin_elementwise_max(A.v, B.v);
  #pragma unroll
  for (int j = 0; j < 4; ++j) B.w[j] = __shfl_xor(A.w[j], 32);
  A.v = __builtin_elementwise_max(A.v, B.v);
}

// One wave == one item. NO __syncthreads anywhere: all LDS is wave-private.
__global__ __launch_bounds__(256, 4)
void core_snapshot_kernel(const int* __restrict__ la,
                          const u16* __restrict__ ws,
                          const float* __restrict__ gb,
                          float* __restrict__ outp)
{
  __shared__ __align__(16) u16 sListAll[4*LSEG];
  __shared__ __align__(16) u16 sEAll[4*ESEG];

  const int tid  = threadIdx.x;
  const int lane = tid & 63;
  const int wv   = tid >> 6;
  const int m    = lane & 15;
  const int quad = lane >> 4;
  const int item = blockIdx.x*4 + wv;
  u16* sList = sListAll + wv*LSEG;
  u16* sE    = sEAll    + wv*ESEG;
  const u16* qt = ws;
  const u16* wt = ws + WT_OFF;

  // prefill private list with 512 (pads gather the key-0 row == reference pad semantics)
  {
    uint4 f = make_uint4(0x02000200u,0x02000200u,0x02000200u,0x02000200u);
    *(uint4*)&sList[lane*16]     = f;
    *(uint4*)&sList[lane*16 + 8] = f;
  }

  // ---- phase 1: 8 chunks, in-register per-core running counts, no barriers ----
  int av[8];
  #pragma unroll
  for (int ch = 0; ch < 8; ++ch) av[ch] = la[item*NQ + ch*64 + lane];
  const u64 lmask = (1ull << lane) - 1ull;
  u32 runbase = 0;     // lane c (<16) holds running count for core c
  #pragma unroll
  for (int ch = 0; ch < 8; ++ch) {
    u32 cnt = 0, intra = 0;
    #pragma unroll
    for (int c = 0; c < 16; ++c) {
      u64 mk = __ballot(av[ch] == c);
      if (lane == c)    cnt   = (u32)__popcll(mk);
      if (av[ch] == c)  intra = (u32)__popcll(mk & lmask);
    }
    u32 base = (u32)__shfl((int)runbase, av[ch]);   // pre-chunk base for my core
    u32 rank = base + intra;
    // transposed: quad q's 16 entries [q*16+k] hold ranks q+4k (contiguous 32 B)
    if (rank < 64) sList[av[ch]*64 + (rank&3)*16 + (rank>>2)] = (u16)(ch*64 + lane);
    runbase += cnt;
  }
  const u32 cntv = runbase;   // lane c: total count of core c

  // ---- phase 2: per-core gather from L2, 8-deep batches, packed-u16 max ----
  const u16* qb = qt + m*8;   // this lane's 8-dim chunk
  for (int c = 0; c < 16; ++c) {
    int cnt = __shfl((int)cntv, c);
    U8 S0, S1;
    S0.u4 = *(const uint4*)&sList[c*64 + quad*16];      // ranks quad+4k, k=0..7  (<32)
    S1.u4 = *(const uint4*)&sList[c*64 + quad*16 + 8];  // k=8..15 (ranks 32..63)
    U8 A; A.v = (u16x8)0;                               // key 0 < all value keys
    {
      U8 T[8];
      #pragma unroll
      for (int k = 0; k < 8; ++k) T[k].u4 = *(const uint4*)(qb + (int)S0.h[k]*NH);
      #pragma unroll
      for (int k = 0; k < 8; ++k) A.v = __builtin_elementwise_max(A.v, T[k].v);
    }
    if (cnt > 32) {   // wave-uniform branch; pads (row 512) give key(+0)
      U8 T[8];
      #pragma unroll
      for (int k = 0; k < 8; ++k) T[k].u4 = *(const uint4*)(qb + (int)S1.h[k]*NH);
      #pragma unroll
      for (int k = 0; k < 8; ++k) A.v = __builtin_elementwise_max(A.v, T[k].v);
    }
    wave_reduce_max(A);
    if (cnt < 64) {   // relu via key(+0) (redundant with pads, kept for robustness)
      U8 Z; Z.v = (u16x8)(u16)0x8000u;
      A.v = __builtin_elementwise_max(A.v, Z.v);
    }
    if (quad == 0) {
      uint4 e;
      e.x = (u32)unkey(A.h[0]) | ((u32)unkey(A.h[1])<<16);
      e.y = (u32)unkey(A.h[2]) | ((u32)unkey(A.h[3])<<16);
      e.z = (u32)unkey(A.h[4]) | ((u32)unkey(A.h[5])<<16);
      e.w = (u32)unkey(A.h[6]) | ((u32)unkey(A.h[7])<<16);
      *(uint4*)&sE[c*ESTRIDE + m*8] = e;
    }
  }

  // ---- phases 3+4 fused per o-tile; H transposed via cross-quad shuffles ----
  bf16x8 af[4];   // E A-fragments (same-wave LDS RAW -> lgkm wait, no barrier)
  #pragma unroll
  for (int ks = 0; ks < 4; ++ks)
    af[ks] = *(const bf16x8*)&sE[m*ESTRIDE + ks*32 + quad*8];
  Frag anf;       // a_norm A-fragment (precomputed, padded K zeros)
  anf.u4 = *(const uint4*)(ws + A_OFF + m*32 + quad*8);

  #pragma unroll
  for (int t = 0; t < 8; ++t) {
    // H tile: C-layout acc[r] = H[core=quad*4+r][o=t*16+m]
    f32x4 acc = {0.f, 0.f, 0.f, 0.f};
    #pragma unroll
    for (int ks = 0; ks < 4; ++ks) {
      bf16x8 bfr = *(const bf16x8*)(wt + (t*16 + m)*NH + ks*32 + quad*8);
      acc = __builtin_amdgcn_mfma_f32_16x16x32_bf16(af[ks], bfr, acc, 0, 0, 0);
    }
    // B-frag for out-GEMM: lane(m,q) j-th elem = H[core=q*8+j][o=t*16+m], q<2
    float d16[4], d32[4], lo[4], hi[4];
    #pragma unroll
    for (int r = 0; r < 4; ++r) {
      d16[r] = __shfl_down(acc[r], 16);
      d32[r] = __shfl_down(acc[r], 32);
    }
    #pragma unroll
    for (int r = 0; r < 4; ++r) {
      lo[r] = (quad == 0) ? acc[r] : d16[r];
      hi[r] = (quad == 0) ? d16[r] : d32[r];
    }
    Frag hb;
    hb.u[0] = pack_rne(lo[0], lo[1]); hb.u[1] = pack_rne(lo[2], lo[3]);
    hb.u[2] = pack_rne(hi[0], hi[1]); hb.u[3] = pack_rne(hi[2], hi[3]);
    if (quad >= 2) { hb.u[0]=0; hb.u[1]=0; hb.u[2]=0; hb.u[3]=0; }  // K-pad: keep 0*0
    float biasv = gb[t*16 + m];
    f32x4 o4 = {biasv, biasv, biasv, biasv};
    o4 = __builtin_amdgcn_mfma_f32_16x16x32_bf16(anf.f, hb.f, o4, 0, 0, 0);
    // C/D: col=lane&15 (o in tile), row=quad*4+reg (core)
    float* op = outp + item*(NC*NH) + t*16 + m;
    #pragma unroll
    for (int r = 0; r < 4; ++r) op[(quad*4 + r)*NH] = o4[r];
  }
}

extern "C" void kernel_launch(void* const* d_in, const int* in_sizes, int n_in,
                              void* d_out, int out_size, void* d_ws, size_t ws_size,
                              hipStream_t stream) {
  const int*   la  = (const int*)d_in[0];    // (2048, 512) int32
  const float* adj = (const float*)d_in[1];  // (16,16) fp32
  const float* qe  = (const float*)d_in[2];  // (513,128) fp32
  const float* gw  = (const float*)d_in[3];  // (128,128) fp32
  const float* gb  = (const float*)d_in[4];  // (128,) fp32
  float* outp = (float*)d_out;               // (2048,16,128) fp32
  u16* ws = (u16*)d_ws;                      // keys + bf16 W + a_norm frag

  int pre_blocks = 1 + (QE_KEYS/8 + GW_ELEMS/8 + 255)/256;   // 42
  prepass_kernel<<<pre_blocks, 256, 0, stream>>>(qe, gw, adj, ws);
  core_snapshot_kernel<<<NB/4, 256, 0, stream>>>(la, ws, gb, outp);
}